// Round 6
// baseline (629.154 us; speedup 1.0000x reference)
//
#include <hip/hip_runtime.h>

#define NPTS 65536
#define BATCH 2
#define CCH 128
#define HIDC 64
#define LDB 520      // k_zr bext row stride u16 (512+8 pad)
#define LDB2 264     // k_q bext row stride u16 (256+8 pad)
#define PLD 130      // k_pack tile row stride u16

typedef unsigned short u16;
typedef unsigned int u32;
typedef __bf16 bf16_t;
typedef bf16_t bf16x8 __attribute__((ext_vector_type(8)));
typedef float f32x4 __attribute__((ext_vector_type(4)));

__device__ __forceinline__ u16 f2bf(float f){
  union { float f; unsigned u; } v; v.f = f;
  unsigned r = v.u + 0x7FFFu + ((v.u >> 16) & 1u);
  return (u16)(r >> 16);
}
__device__ __forceinline__ float bf2f(u16 u){
  union { unsigned u; float f; } v; v.u = ((unsigned)u) << 16; return v.f;
}
__device__ __forceinline__ u32 pkrn(float a, float b){
  union { float f; u32 u; } ua, ub; ua.f = a; ub.f = b;
  return ((ua.u + 0x8000u) >> 16) | ((ub.u + 0x8000u) & 0xffff0000u);
}
__device__ __forceinline__ float sigmoidf_(float v){ return 1.f/(1.f+__expf(-v)); }
__device__ __forceinline__ float tanhf_(float v){
  v = fminf(10.f, fmaxf(-10.f, v));
  float e = __expf(2.f*v);
  return (e-1.f)/(e+1.f);
}

// A matrices (bf16), fragment-permuted. First 98304: Az|Ar|Aq at K=512
// (phys k = s*32+quad*8+t; j=pk>>7, chunk=(pk>>3)&15, tt=pk&7;
//  orig=chunk*32+j*8+tt; c=orig>>2, m=orig&3). Then 16384: Aqrh at K=256.
__global__ __launch_bounds__(256) void kprep(
    const float* __restrict__ wz, const float* __restrict__ wzp, const float* __restrict__ bzp,
    const float* __restrict__ wr, const float* __restrict__ wrp, const float* __restrict__ brp,
    const float* __restrict__ wq, const float* __restrict__ wqp, const float* __restrict__ bqp,
    u16* __restrict__ A){
  int idx = blockIdx.x*256 + threadIdx.x;          // 0..114687
  if (idx < 98304){
    int t = idx & 7, o = (idx>>3)&63, quad = (idx>>9)&3, s = (idx>>11)&15, g = idx>>15;
    int pk = s*32 + quad*8 + t;
    int j = pk>>7, chunk = (pk>>3)&15, tt = pk&7;
    int orig = chunk*32 + j*8 + tt;
    int c = orig>>2, m = orig&3;
    const float* W  = (g==0)? wz  : (g==1)? wr  : wq;
    const float* wp = (g==0)? wzp : (g==1)? wrp : wqp;
    const float* bp = (g==0)? bzp : (g==1)? brp : bqp;
    float coef = m ? wp[c*3 + m - 1] : bp[c];
    A[idx] = f2bf(W[o*CCH + c] * coef);
  } else {
    int i2 = idx - 98304;
    int t = i2 & 7, o = (i2>>3)&63, quad = (i2>>9)&3, s = (i2>>11)&7;
    int k2 = s*32 + quad*8 + t;
    int j = k2>>6, chunk = (k2>>3)&7, tt = k2&7;
    int orig = chunk*32 + j*8 + tt;
    int c = orig>>2, m = orig&3;                   // c in [0,64): rh channels
    float coef = m ? wqp[c*3 + m - 1] : bqp[c];
    A[idx] = f2bf(wq[o*CCH + c] * coef);
  }
}

// Transpose h,x [B,64,N] fp32 -> hxT [B,N,128] bf16 rows.
__global__ __launch_bounds__(256) void k_pack(const float* __restrict__ h,
    const float* __restrict__ x, u16* __restrict__ hxT){
  __shared__ __align__(16) u16 tile[64*PLD];
  int tid = threadIdx.x;
  int b = blockIdx.x >> 10, n0 = (blockIdx.x & 1023) << 6;
  #pragma unroll
  for (int i = 0; i < 8; ++i){
    int cc = (tid>>4) + i*16;                      // 0..127
    int nn = (tid & 15)*4;
    const float* src = (cc < HIDC)
        ? (h + (((size_t)(b*HIDC + cc))<<16) + n0 + nn)
        : (x + (((size_t)(b*HIDC + cc - HIDC))<<16) + n0 + nn);
    float4 v = *(const float4*)src;
    tile[(nn+0)*PLD + cc] = f2bf(v.x);
    tile[(nn+1)*PLD + cc] = f2bf(v.y);
    tile[(nn+2)*PLD + cc] = f2bf(v.z);
    tile[(nn+3)*PLD + cc] = f2bf(v.w);
  }
  __syncthreads();
  #pragma unroll
  for (int i = 0; i < 4; ++i){
    int tsk = tid + (i<<8);                        // 0..1023: 64 n x 16 chunks
    int n = tsk>>4, ch = (tsk&15)*8;
    uint4 v = *(const uint4*)(tile + n*PLD + ch);
    *(uint4*)(hxT + (((size_t)(b<<16) + n0 + n)<<7) + ch) = v;
  }
}

#define ACCUM(gv, RX, RY, RZ) { \
  u32 dw_[4] = {gv.x, gv.y, gv.z, gv.w}; \
  _Pragma("unroll") \
  for (int q_ = 0; q_ < 4; ++q_){ \
    union { u32 u; float f; } lo_, hi_; \
    lo_.u = dw_[q_] << 16; hi_.u = dw_[q_] & 0xffff0000u; \
    m0[2*q_]   += lo_.f; mx[2*q_]   += (RX)*lo_.f; my[2*q_]   += (RY)*lo_.f; mz[2*q_]   += (RZ)*lo_.f; \
    m0[2*q_+1] += hi_.f; mx[2*q_+1] += (RX)*hi_.f; my[2*q_+1] += (RY)*hi_.f; mz[2*q_+1] += (RZ)*hi_.f; \
  } }

#define PACKROW(row, CHOFF, STRIDE) { \
  _Pragma("unroll") \
  for (int j_ = 0; j_ < 4; ++j_){ \
    int ca_ = 2*j_, cb_ = 2*j_+1; \
    uint4 v_; \
    v_.x = pkrn(m0[ca_], mx[ca_]); v_.y = pkrn(my[ca_], mz[ca_]); \
    v_.z = pkrn(m0[cb_], mx[cb_]); v_.w = pkrn(my[cb_], mz[cb_]); \
    *(uint4*)((row) + j_*(STRIDE) + (CHOFF)) = v_; \
  } }

#define LOADREL(RX, RY, RZ, JJ, P, N0) { \
  float cx_ = xb[(N0)+(P)], cy_ = xb[NPTS+(N0)+(P)], cz_ = xb[2*NPTS+(N0)+(P)]; \
  RX[0]=xb[JJ.x]-cx_; RY[0]=xb[NPTS+JJ.x]-cy_; RZ[0]=xb[2*NPTS+JJ.x]-cz_; \
  RX[1]=xb[JJ.y]-cx_; RY[1]=xb[NPTS+JJ.y]-cy_; RZ[1]=xb[2*NPTS+JJ.y]-cz_; \
  RX[2]=xb[JJ.z]-cx_; RY[2]=xb[NPTS+JJ.z]-cy_; RZ[2]=xb[2*NPTS+JJ.z]-cz_; \
  RX[3]=xb[JJ.w]-cx_; RY[3]=xb[NPTS+JJ.w]-cy_; RZ[3]=xb[2*NPTS+JJ.w]-cz_; }

// z & r gates + q x-partial. Persistent: 1024 blocks x 4 tiles of 32 points,
// cross-tile software pipeline (tile t+1 loads issued during tile t compute).
__global__ __launch_bounds__(256, 4) void k_zr(
    const float* __restrict__ xyz, const float* __restrict__ h,
    const int* __restrict__ knn,
    const float* __restrict__ bz_out, const float* __restrict__ br_out,
    const u16* __restrict__ Azr,    // Az 0, Ar +32768, Aq +65536
    const u16* __restrict__ hxT, u16* __restrict__ rhT, u32* __restrict__ zq_ws)
{
  __shared__ __align__(16) u16 bext[32*LDB];       // 33280 B
  __shared__ __align__(16) u16 rhst[32*72];        //  4608 B

  int tid = threadIdx.x; int lane = tid & 63; int wv = tid >> 6;
  int bid = blockIdx.x;
  int b = bid >> 9;
  int nbase = (bid & 511) << 7;                    // 4 tiles * 32 points
  size_t bN = (size_t)b * NPTS;
  const float* xb = xyz + (size_t)b*3*NPTS;
  const u16* hxTb = hxT + (bN << 7);
  const int4* knn4 = (const int4*)knn + bN;
  int pA = tid >> 4, chk8 = (tid & 15)*8;
  int pB = pA + 16;
  const u16* cbase = hxTb + chk8;
  int l15 = lane & 15, quad = lane >> 4;
  int orow = wv*16 + l15;

  int4 jA, jB;
  float rAx[4], rAy[4], rAz[4], rBx[4], rBy[4], rBz[4];
  uint4 ga[4], gb[4];

  // prologue: full preload of tile 0
  {
    int n0 = nbase;
    jA = knn4[n0 + pA]; jB = knn4[n0 + pB];
    LOADREL(rAx, rAy, rAz, jA, pA, n0);
    LOADREL(rBx, rBy, rBz, jB, pB, n0);
    ga[0] = *(const uint4*)(cbase + (((size_t)jA.x)<<7));
    ga[1] = *(const uint4*)(cbase + (((size_t)jA.y)<<7));
    ga[2] = *(const uint4*)(cbase + (((size_t)jA.z)<<7));
    ga[3] = *(const uint4*)(cbase + (((size_t)jA.w)<<7));
    gb[0] = *(const uint4*)(cbase + (((size_t)jB.x)<<7));
    gb[1] = *(const uint4*)(cbase + (((size_t)jB.y)<<7));
    gb[2] = *(const uint4*)(cbase + (((size_t)jB.z)<<7));
    gb[3] = *(const uint4*)(cbase + (((size_t)jB.w)<<7));
  }

  for (int t = 0; t < 4; ++t){
    int n0c = nbase + (t<<5);
    int n0n = n0c + 32;
    bool more = (t < 3);
    int4 jAn = jA, jBn = jB;
    if (more){ jAn = knn4[n0n + pA]; jBn = knn4[n0n + pB]; }

    // moments(t) from registers -> bext
    {
      float m0[8]={0,0,0,0,0,0,0,0}, mx[8]={0,0,0,0,0,0,0,0};
      float my[8]={0,0,0,0,0,0,0,0}, mz[8]={0,0,0,0,0,0,0,0};
      ACCUM(ga[0], rAx[0], rAy[0], rAz[0]);
      ACCUM(ga[1], rAx[1], rAy[1], rAz[1]);
      ACCUM(ga[2], rAx[2], rAy[2], rAz[2]);
      ACCUM(ga[3], rAx[3], rAy[3], rAz[3]);
      PACKROW(bext + pA*LDB, chk8, 128);
    }
    {
      float m0[8]={0,0,0,0,0,0,0,0}, mx[8]={0,0,0,0,0,0,0,0};
      float my[8]={0,0,0,0,0,0,0,0}, mz[8]={0,0,0,0,0,0,0,0};
      ACCUM(gb[0], rBx[0], rBy[0], rBz[0]);
      ACCUM(gb[1], rBx[1], rBy[1], rBz[1]);
      ACCUM(gb[2], rBx[2], rBy[2], rBz[2]);
      ACCUM(gb[3], rBx[3], rBy[3], rBz[3]);
      PACKROW(bext + pB*LDB, chk8, 128);
    }

    // issue gathers for t+1 (cover = MFMA + epilogue of tile t)
    uint4 gan[4], gbn[4];
    if (more){
      gan[0] = *(const uint4*)(cbase + (((size_t)jAn.x)<<7));
      gan[1] = *(const uint4*)(cbase + (((size_t)jAn.y)<<7));
      gan[2] = *(const uint4*)(cbase + (((size_t)jAn.z)<<7));
      gan[3] = *(const uint4*)(cbase + (((size_t)jAn.w)<<7));
      gbn[0] = *(const uint4*)(cbase + (((size_t)jBn.x)<<7));
      gbn[1] = *(const uint4*)(cbase + (((size_t)jBn.y)<<7));
      gbn[2] = *(const uint4*)(cbase + (((size_t)jBn.z)<<7));
      gbn[3] = *(const uint4*)(cbase + (((size_t)jBn.w)<<7));
    }
    __syncthreads();

    // MFMA: z,r over K=512; q x-part over s&2 slices (c>=64)
    f32x4 accz[2], accr[2], accq[2];
    #pragma unroll
    for (int nt = 0; nt < 2; ++nt){
      accz[nt] = (f32x4){0,0,0,0}; accr[nt] = (f32x4){0,0,0,0}; accq[nt] = (f32x4){0,0,0,0};
    }
    #pragma unroll
    for (int s = 0; s < 16; ++s){
      bf16x8 az = *(const bf16x8*)(Azr + ((s*4 + quad)*64 + orow)*8);
      bf16x8 ar = *(const bf16x8*)(Azr + 32768 + ((s*4 + quad)*64 + orow)*8);
      if (s & 2){
        bf16x8 aq = *(const bf16x8*)(Azr + 65536 + ((s*4 + quad)*64 + orow)*8);
        #pragma unroll
        for (int nt = 0; nt < 2; ++nt){
          bf16x8 bb = *(const bf16x8*)(bext + (nt*16 + l15)*LDB + s*32 + quad*8);
          accz[nt] = __builtin_amdgcn_mfma_f32_16x16x32_bf16(az, bb, accz[nt], 0, 0, 0);
          accr[nt] = __builtin_amdgcn_mfma_f32_16x16x32_bf16(ar, bb, accr[nt], 0, 0, 0);
          accq[nt] = __builtin_amdgcn_mfma_f32_16x16x32_bf16(aq, bb, accq[nt], 0, 0, 0);
        }
      } else {
        #pragma unroll
        for (int nt = 0; nt < 2; ++nt){
          bf16x8 bb = *(const bf16x8*)(bext + (nt*16 + l15)*LDB + s*32 + quad*8);
          accz[nt] = __builtin_amdgcn_mfma_f32_16x16x32_bf16(az, bb, accz[nt], 0, 0, 0);
          accr[nt] = __builtin_amdgcn_mfma_f32_16x16x32_bf16(ar, bb, accr[nt], 0, 0, 0);
        }
      }
    }

    // rel coords for t+1 (xyz is L2-resident; covered by epilogue)
    if (more){
      LOADREL(rAx, rAy, rAz, jAn, pA, n0n);
      LOADREL(rBx, rBy, rBz, jBn, pB, n0n);
    }

    // epilogue(t): z|qx packed direct stores, rh via LDS transpose
    #pragma unroll
    for (int nt = 0; nt < 2; ++nt){
      #pragma unroll
      for (int reg = 0; reg < 4; ++reg){
        int o = wv*16 + quad*4 + reg;             // C/D: row = quad*4+reg
        int p = nt*16 + l15;                      // col = lane&15
        size_t idx = (((size_t)(b*HIDC + o))<<16) + n0c + p;
        float zf = sigmoidf_(accz[nt][reg] + bz_out[o]);
        float rf = sigmoidf_(accr[nt][reg] + br_out[o]);
        float hv = h[idx];
        zq_ws[idx] = pkrn(zf, accq[nt][reg]);     // z lo16, qx hi16 (bias in k_q)
        rhst[p*72 + o] = f2bf(rf * hv);
      }
    }
    __syncthreads();
    {
      int p = tid >> 3, ch = (tid & 7)*8;
      uint4 v = *(const uint4*)(rhst + p*72 + ch);
      *(uint4*)(rhT + ((bN + n0c + p)<<6) + ch) = v;
    }
    if (more){
      jA = jAn; jB = jBn;
      #pragma unroll
      for (int i = 0; i < 4; ++i){ ga[i] = gan[i]; gb[i] = gbn[i]; }
    }
  }
}

// q gate (rh gather) + final combine. Persistent: 1024 blocks x 4 tiles of 32.
__global__ __launch_bounds__(256, 4) void k_q(
    const float* __restrict__ xyz, const float* __restrict__ h,
    const int* __restrict__ knn,
    const float* __restrict__ bq_out,
    const u16* __restrict__ Aqrh,
    const u16* __restrict__ rhT, const u32* __restrict__ zq_ws,
    float* __restrict__ out)
{
  __shared__ __align__(16) u16 bext[32*LDB2];      // 16896 B

  int tid = threadIdx.x; int lane = tid & 63; int wv = tid >> 6;
  int bid = blockIdx.x;
  int b = bid >> 9;
  int nbase = (bid & 511) << 7;
  size_t bN = (size_t)b * NPTS;
  const float* xb = xyz + (size_t)b*3*NPTS;
  const u16* rhTb = rhT + (bN << 6);
  const int4* knn4 = (const int4*)knn + bN;
  int pt = tid >> 3, chk8 = (tid & 7)*8;
  const u16* cbase = rhTb + chk8;
  int l15 = lane & 15, quad = lane >> 4;
  int orow = wv*16 + l15;

  int4 jj;
  float rx[4], ry[4], rz[4];
  uint4 g[4];

  {
    int n0 = nbase;
    jj = knn4[n0 + pt];
    LOADREL(rx, ry, rz, jj, pt, n0);
    g[0] = *(const uint4*)(cbase + (((size_t)jj.x)<<6));
    g[1] = *(const uint4*)(cbase + (((size_t)jj.y)<<6));
    g[2] = *(const uint4*)(cbase + (((size_t)jj.z)<<6));
    g[3] = *(const uint4*)(cbase + (((size_t)jj.w)<<6));
  }

  for (int t = 0; t < 4; ++t){
    int n0c = nbase + (t<<5);
    int n0n = n0c + 32;
    bool more = (t < 3);
    int4 jn = jj;
    if (more){ jn = knn4[n0n + pt]; }

    {
      float m0[8]={0,0,0,0,0,0,0,0}, mx[8]={0,0,0,0,0,0,0,0};
      float my[8]={0,0,0,0,0,0,0,0}, mz[8]={0,0,0,0,0,0,0,0};
      ACCUM(g[0], rx[0], ry[0], rz[0]);
      ACCUM(g[1], rx[1], ry[1], rz[1]);
      ACCUM(g[2], rx[2], ry[2], rz[2]);
      ACCUM(g[3], rx[3], ry[3], rz[3]);
      PACKROW(bext + pt*LDB2, chk8, 64);
    }

    uint4 gn[4];
    if (more){
      gn[0] = *(const uint4*)(cbase + (((size_t)jn.x)<<6));
      gn[1] = *(const uint4*)(cbase + (((size_t)jn.y)<<6));
      gn[2] = *(const uint4*)(cbase + (((size_t)jn.z)<<6));
      gn[3] = *(const uint4*)(cbase + (((size_t)jn.w)<<6));
    }
    __syncthreads();

    f32x4 acc[2];
    #pragma unroll
    for (int nt = 0; nt < 2; ++nt) acc[nt] = (f32x4){0,0,0,0};
    #pragma unroll
    for (int s = 0; s < 8; ++s){
      bf16x8 aq = *(const bf16x8*)(Aqrh + ((s*4 + quad)*64 + orow)*8);
      #pragma unroll
      for (int nt = 0; nt < 2; ++nt){
        bf16x8 bb = *(const bf16x8*)(bext + (nt*16 + l15)*LDB2 + s*32 + quad*8);
        acc[nt] = __builtin_amdgcn_mfma_f32_16x16x32_bf16(aq, bb, acc[nt], 0, 0, 0);
      }
    }

    if (more){
      LOADREL(rx, ry, rz, jn, pt, n0n);
    }

    #pragma unroll
    for (int nt = 0; nt < 2; ++nt){
      #pragma unroll
      for (int reg = 0; reg < 4; ++reg){
        int o = wv*16 + quad*4 + reg;
        int p = nt*16 + l15;
        size_t idx = (((size_t)(b*HIDC + o))<<16) + n0c + p;
        u32 v = zq_ws[idx];
        float zf  = bf2f((u16)(v & 0xffffu));
        float qxv = bf2f((u16)(v >> 16));
        float qf = tanhf_(acc[nt][reg] + bq_out[o] + qxv);
        float hv = h[idx];
        out[idx] = (1.f - zf)*hv + zf*qf;
      }
    }
    __syncthreads();   // guard bext reuse by next tile's moments
    if (more){
      jj = jn;
      #pragma unroll
      for (int i = 0; i < 4; ++i) g[i] = gn[i];
    }
  }
}

extern "C" void kernel_launch(void* const* d_in, const int* in_sizes, int n_in,
                              void* d_out, int out_size, void* d_ws, size_t ws_size,
                              hipStream_t stream){
  const float* xyz    = (const float*)d_in[0];
  const float* h      = (const float*)d_in[1];
  const float* x      = (const float*)d_in[2];
  const int*   knn    = (const int*)d_in[3];
  const float* wz_pos = (const float*)d_in[4];
  const float* bz_pos = (const float*)d_in[5];
  const float* wz_out = (const float*)d_in[6];
  const float* bz_out = (const float*)d_in[7];
  const float* wr_pos = (const float*)d_in[8];
  const float* br_pos = (const float*)d_in[9];
  const float* wr_out = (const float*)d_in[10];
  const float* br_out = (const float*)d_in[11];
  const float* wq_pos = (const float*)d_in[12];
  const float* bq_pos = (const float*)d_in[13];
  const float* wq_out = (const float*)d_in[14];
  const float* bq_out = (const float*)d_in[15];
  float* out = (float*)d_out;

  // ws (u16 units): hxT[16777216] | rhT[8388608] | zq(u32)[8388608] | A[114688]
  u16* ws   = (u16*)d_ws;
  u16* hxT  = ws;
  u16* rhT  = ws + 16777216;
  u32* zq   = (u32*)(ws + 25165824);
  u16* A    = ws + 41943040;

  kprep<<<448, 256, 0, stream>>>(wz_out, wz_pos, bz_pos, wr_out, wr_pos, br_pos,
                                 wq_out, wq_pos, bq_pos, A);
  k_pack<<<2048, 256, 0, stream>>>(h, x, hxT);
  k_zr<<<1024, 256, 0, stream>>>(xyz, h, knn, bz_out, br_out, A, hxT, rhT, zq);
  k_q<<<1024, 256, 0, stream>>>(xyz, h, knn, bq_out, A + 98304, rhT, zq, out);
}

// Round 7
// 256.915 us; speedup vs baseline: 2.4489x; 2.4489x over previous
//
#include <hip/hip_runtime.h>

#define NPTS 65536
#define BATCH 2
#define CCH 128
#define HIDC 64
#define LDB 520      // k_zr bext row stride u16 (512+8 pad)
#define LDB2 264     // k_q bext row stride u16 (256+8 pad)
#define PLD 130      // k_pack tile row stride u16

typedef unsigned short u16;
typedef unsigned int u32;
typedef __bf16 bf16_t;
typedef bf16_t bf16x8 __attribute__((ext_vector_type(8)));
typedef float f32x4 __attribute__((ext_vector_type(4)));

__device__ __forceinline__ u16 f2bf(float f){
  union { float f; unsigned u; } v; v.f = f;
  unsigned r = v.u + 0x7FFFu + ((v.u >> 16) & 1u);
  return (u16)(r >> 16);
}
__device__ __forceinline__ float bf2f(u16 u){
  union { unsigned u; float f; } v; v.u = ((unsigned)u) << 16; return v.f;
}
__device__ __forceinline__ u32 pkrn(float a, float b){
  union { float f; u32 u; } ua, ub; ua.f = a; ub.f = b;
  return ((ua.u + 0x8000u) >> 16) | ((ub.u + 0x8000u) & 0xffff0000u);
}
__device__ __forceinline__ float sigmoidf_(float v){ return 1.f/(1.f+__expf(-v)); }
__device__ __forceinline__ float tanhf_(float v){
  v = fminf(10.f, fmaxf(-10.f, v));
  float e = __expf(2.f*v);
  return (e-1.f)/(e+1.f);
}

// A matrices (bf16), fragment-permuted. First 98304: Az|Ar|Aq at K=512
// (phys k = s*32+quad*8+t; j=pk>>7, chunk=(pk>>3)&15, tt=pk&7;
//  orig=chunk*32+j*8+tt; c=orig>>2, m=orig&3). Then 16384: Aqrh at K=256.
__global__ __launch_bounds__(256) void kprep(
    const float* __restrict__ wz, const float* __restrict__ wzp, const float* __restrict__ bzp,
    const float* __restrict__ wr, const float* __restrict__ wrp, const float* __restrict__ brp,
    const float* __restrict__ wq, const float* __restrict__ wqp, const float* __restrict__ bqp,
    u16* __restrict__ A){
  int idx = blockIdx.x*256 + threadIdx.x;          // 0..114687
  if (idx < 98304){
    int t = idx & 7, o = (idx>>3)&63, quad = (idx>>9)&3, s = (idx>>11)&15, g = idx>>15;
    int pk = s*32 + quad*8 + t;
    int j = pk>>7, chunk = (pk>>3)&15, tt = pk&7;
    int orig = chunk*32 + j*8 + tt;
    int c = orig>>2, m = orig&3;
    const float* W  = (g==0)? wz  : (g==1)? wr  : wq;
    const float* wp = (g==0)? wzp : (g==1)? wrp : wqp;
    const float* bp = (g==0)? bzp : (g==1)? brp : bqp;
    float coef = m ? wp[c*3 + m - 1] : bp[c];
    A[idx] = f2bf(W[o*CCH + c] * coef);
  } else {
    int i2 = idx - 98304;
    int t = i2 & 7, o = (i2>>3)&63, quad = (i2>>9)&3, s = (i2>>11)&7;
    int k2 = s*32 + quad*8 + t;
    int j = k2>>6, chunk = (k2>>3)&7, tt = k2&7;
    int orig = chunk*32 + j*8 + tt;
    int c = orig>>2, m = orig&3;                   // c in [0,64): rh channels
    float coef = m ? wqp[c*3 + m - 1] : bqp[c];
    A[idx] = f2bf(wq[o*CCH + c] * coef);
  }
}

// Transpose h,x [B,64,N] fp32 -> hxT [B,N,128] bf16 rows.
__global__ __launch_bounds__(256) void k_pack(const float* __restrict__ h,
    const float* __restrict__ x, u16* __restrict__ hxT){
  __shared__ __align__(16) u16 tile[64*PLD];
  int tid = threadIdx.x;
  int b = blockIdx.x >> 10, n0 = (blockIdx.x & 1023) << 6;
  #pragma unroll
  for (int i = 0; i < 8; ++i){
    int cc = (tid>>4) + i*16;                      // 0..127
    int nn = (tid & 15)*4;
    const float* src = (cc < HIDC)
        ? (h + (((size_t)(b*HIDC + cc))<<16) + n0 + nn)
        : (x + (((size_t)(b*HIDC + cc - HIDC))<<16) + n0 + nn);
    float4 v = *(const float4*)src;
    tile[(nn+0)*PLD + cc] = f2bf(v.x);
    tile[(nn+1)*PLD + cc] = f2bf(v.y);
    tile[(nn+2)*PLD + cc] = f2bf(v.z);
    tile[(nn+3)*PLD + cc] = f2bf(v.w);
  }
  __syncthreads();
  #pragma unroll
  for (int i = 0; i < 4; ++i){
    int tsk = tid + (i<<8);                        // 0..1023: 64 n x 16 chunks
    int n = tsk>>4, ch = (tsk&15)*8;
    uint4 v = *(const uint4*)(tile + n*PLD + ch);
    *(uint4*)(hxT + (((size_t)(b<<16) + n0 + n)<<7) + ch) = v;
  }
}

#define ACCUM(gv, rv) { \
  u32 dw_[4] = {gv.x, gv.y, gv.z, gv.w}; \
  _Pragma("unroll") \
  for (int q_ = 0; q_ < 4; ++q_){ \
    union { u32 u; float f; } lo_, hi_; \
    lo_.u = dw_[q_] << 16; hi_.u = dw_[q_] & 0xffff0000u; \
    m0[2*q_]   += lo_.f; mx[2*q_]   += rv.x*lo_.f; my[2*q_]   += rv.y*lo_.f; mz[2*q_]   += rv.z*lo_.f; \
    m0[2*q_+1] += hi_.f; mx[2*q_+1] += rv.x*hi_.f; my[2*q_+1] += rv.y*hi_.f; mz[2*q_+1] += rv.z*hi_.f; \
  } }

#define PACKROW(row, CHOFF, STRIDE) { \
  _Pragma("unroll") \
  for (int j_ = 0; j_ < 4; ++j_){ \
    int ca_ = 2*j_, cb_ = 2*j_+1; \
    uint4 v_; \
    v_.x = pkrn(m0[ca_], mx[ca_]); v_.y = pkrn(my[ca_], mz[ca_]); \
    v_.z = pkrn(m0[cb_], mx[cb_]); v_.w = pkrn(my[cb_], mz[cb_]); \
    *(uint4*)((row) + j_*(STRIDE) + (CHOFF)) = v_; \
  } }

// Cooperative knn+rel staging for one 32-point tile (tid<128: p=tid>>2, k=tid&3).
#define COOPLOAD(N0, BUFI) \
  if (tid < 128){ \
    int p_ = tid >> 2; \
    int j_ = knn[((bN + (N0) + p_) << 2) + (tid & 3)]; \
    jlds[BUFI][tid] = j_; \
    float cx_ = xb[(N0)+p_], cy_ = xb[NPTS+(N0)+p_], cz_ = xb[2*NPTS+(N0)+p_]; \
    relk[BUFI][tid] = make_float4(xb[j_]-cx_, xb[NPTS+j_]-cy_, xb[2*NPTS+j_]-cz_, 0.f); \
  }

// z & r gates + q x-partial. Persistent: 1024 blocks x 4 tiles of 32 points.
// Cross-tile pipeline: tile t+1 row-gathers prefetched into VGPRs under
// MFMA(t)+epilogue(t); knn/xyz staging stays cooperative (R6 lesson).
__global__ __launch_bounds__(256) void k_zr(
    const float* __restrict__ xyz, const float* __restrict__ h,
    const int* __restrict__ knn,
    const float* __restrict__ bz_out, const float* __restrict__ br_out,
    const u16* __restrict__ Azr,    // Az 0, Ar +32768, Aq +65536
    const u16* __restrict__ hxT, u16* __restrict__ rhT, u32* __restrict__ zq_ws)
{
  __shared__ __align__(16) u16 bext[32*LDB];       // 33280 B
  __shared__ __align__(16) u16 rhst[32*72];        //  4608 B
  __shared__ __align__(16) float4 relk[2][128];    //  4096 B
  __shared__ __align__(16) int jlds[2][128];       //  1024 B

  int tid = threadIdx.x; int lane = tid & 63; int wv = tid >> 6;
  int bid = blockIdx.x;
  int b = bid >> 9;
  int nbase = (bid & 511) << 7;                    // 4 tiles * 32 points
  size_t bN = (size_t)b * NPTS;
  const float* xb = xyz + (size_t)b*3*NPTS;
  const u16* hxTb = hxT + (bN << 7);
  int pA = tid >> 4, chk8 = (tid & 15)*8;
  int pB = pA + 16;
  const u16* cbase = hxTb + chk8;
  int l15 = lane & 15, quad = lane >> 4;
  int orow = wv*16 + l15;

  uint4 ga[4], gb[4];

  // prologue: stage tile 0, then issue its gathers
  COOPLOAD(nbase, 0);
  __syncthreads();
  {
    int4 jA = ((const int4*)jlds[0])[pA];
    int4 jB = ((const int4*)jlds[0])[pB];
    ga[0] = *(const uint4*)(cbase + (((size_t)jA.x)<<7));
    ga[1] = *(const uint4*)(cbase + (((size_t)jA.y)<<7));
    ga[2] = *(const uint4*)(cbase + (((size_t)jA.z)<<7));
    ga[3] = *(const uint4*)(cbase + (((size_t)jA.w)<<7));
    gb[0] = *(const uint4*)(cbase + (((size_t)jB.x)<<7));
    gb[1] = *(const uint4*)(cbase + (((size_t)jB.y)<<7));
    gb[2] = *(const uint4*)(cbase + (((size_t)jB.z)<<7));
    gb[3] = *(const uint4*)(cbase + (((size_t)jB.w)<<7));
  }

  for (int t = 0; t < 4; ++t){
    int n0c = nbase + (t<<5);
    bool more = (t < 3);
    int cur = t & 1, nxt = (t+1) & 1;

    // cooperative staging for tile t+1 (coalesced knn + xyz)
    if (more){ COOPLOAD(n0c + 32, nxt); }

    // moments(t): registers + LDS rel -> bext
    {
      float4 r0 = relk[cur][pA*4+0], r1 = relk[cur][pA*4+1];
      float4 r2 = relk[cur][pA*4+2], r3 = relk[cur][pA*4+3];
      float m0[8]={0,0,0,0,0,0,0,0}, mx[8]={0,0,0,0,0,0,0,0};
      float my[8]={0,0,0,0,0,0,0,0}, mz[8]={0,0,0,0,0,0,0,0};
      ACCUM(ga[0], r0); ACCUM(ga[1], r1); ACCUM(ga[2], r2); ACCUM(ga[3], r3);
      PACKROW(bext + pA*LDB, chk8, 128);
    }
    {
      float4 r0 = relk[cur][pB*4+0], r1 = relk[cur][pB*4+1];
      float4 r2 = relk[cur][pB*4+2], r3 = relk[cur][pB*4+3];
      float m0[8]={0,0,0,0,0,0,0,0}, mx[8]={0,0,0,0,0,0,0,0};
      float my[8]={0,0,0,0,0,0,0,0}, mz[8]={0,0,0,0,0,0,0,0};
      ACCUM(gb[0], r0); ACCUM(gb[1], r1); ACCUM(gb[2], r2); ACCUM(gb[3], r3);
      PACKROW(bext + pB*LDB, chk8, 128);
    }
    __syncthreads();   // A: bext(t) ready; jlds/relk[nxt] ready

    // issue gathers(t+1): covered by MFMA(t) + epilogue(t)
    if (more){
      int4 jA = ((const int4*)jlds[nxt])[pA];
      int4 jB = ((const int4*)jlds[nxt])[pB];
      ga[0] = *(const uint4*)(cbase + (((size_t)jA.x)<<7));
      ga[1] = *(const uint4*)(cbase + (((size_t)jA.y)<<7));
      ga[2] = *(const uint4*)(cbase + (((size_t)jA.z)<<7));
      ga[3] = *(const uint4*)(cbase + (((size_t)jA.w)<<7));
      gb[0] = *(const uint4*)(cbase + (((size_t)jB.x)<<7));
      gb[1] = *(const uint4*)(cbase + (((size_t)jB.y)<<7));
      gb[2] = *(const uint4*)(cbase + (((size_t)jB.z)<<7));
      gb[3] = *(const uint4*)(cbase + (((size_t)jB.w)<<7));
    }

    // MFMA(t): z,r over K=512; q x-part over s&2 slices (c>=64)
    f32x4 accz[2], accr[2], accq[2];
    #pragma unroll
    for (int nt = 0; nt < 2; ++nt){
      accz[nt] = (f32x4){0,0,0,0}; accr[nt] = (f32x4){0,0,0,0}; accq[nt] = (f32x4){0,0,0,0};
    }
    #pragma unroll
    for (int s = 0; s < 16; ++s){
      bf16x8 az = *(const bf16x8*)(Azr + ((s*4 + quad)*64 + orow)*8);
      bf16x8 ar = *(const bf16x8*)(Azr + 32768 + ((s*4 + quad)*64 + orow)*8);
      if (s & 2){
        bf16x8 aq = *(const bf16x8*)(Azr + 65536 + ((s*4 + quad)*64 + orow)*8);
        #pragma unroll
        for (int nt = 0; nt < 2; ++nt){
          bf16x8 bb = *(const bf16x8*)(bext + (nt*16 + l15)*LDB + s*32 + quad*8);
          accz[nt] = __builtin_amdgcn_mfma_f32_16x16x32_bf16(az, bb, accz[nt], 0, 0, 0);
          accr[nt] = __builtin_amdgcn_mfma_f32_16x16x32_bf16(ar, bb, accr[nt], 0, 0, 0);
          accq[nt] = __builtin_amdgcn_mfma_f32_16x16x32_bf16(aq, bb, accq[nt], 0, 0, 0);
        }
      } else {
        #pragma unroll
        for (int nt = 0; nt < 2; ++nt){
          bf16x8 bb = *(const bf16x8*)(bext + (nt*16 + l15)*LDB + s*32 + quad*8);
          accz[nt] = __builtin_amdgcn_mfma_f32_16x16x32_bf16(az, bb, accz[nt], 0, 0, 0);
          accr[nt] = __builtin_amdgcn_mfma_f32_16x16x32_bf16(ar, bb, accr[nt], 0, 0, 0);
        }
      }
    }

    // epilogue(t): zq direct stores, rh staged for coalesced transpose write
    #pragma unroll
    for (int nt = 0; nt < 2; ++nt){
      #pragma unroll
      for (int reg = 0; reg < 4; ++reg){
        int o = wv*16 + quad*4 + reg;             // C/D: row = quad*4+reg
        int p = nt*16 + l15;                      // col = lane&15
        size_t idx = (((size_t)(b*HIDC + o))<<16) + n0c + p;
        float zf = sigmoidf_(accz[nt][reg] + bz_out[o]);
        float rf = sigmoidf_(accr[nt][reg] + br_out[o]);
        float hv = h[idx];
        zq_ws[idx] = pkrn(zf, accq[nt][reg]);     // z lo16, qx hi16 (bias in k_q)
        rhst[p*72 + o] = f2bf(rf * hv);
      }
    }
    __syncthreads();   // C: rhst ready; bext free for moments(t+1)
    {
      int p = tid >> 3, ch = (tid & 7)*8;
      uint4 v = *(const uint4*)(rhst + p*72 + ch);
      *(uint4*)(rhT + ((bN + n0c + p)<<6) + ch) = v;
    }
  }
}

// q gate (rh gather) + final combine. Persistent: 1024 blocks x 4 tiles of 32.
__global__ __launch_bounds__(256) void k_q(
    const float* __restrict__ xyz, const float* __restrict__ h,
    const int* __restrict__ knn,
    const float* __restrict__ bq_out,
    const u16* __restrict__ Aqrh,
    const u16* __restrict__ rhT, const u32* __restrict__ zq_ws,
    float* __restrict__ out)
{
  __shared__ __align__(16) u16 bext[32*LDB2];      // 16896 B
  __shared__ __align__(16) float4 relk[2][128];
  __shared__ __align__(16) int jlds[2][128];

  int tid = threadIdx.x; int lane = tid & 63; int wv = tid >> 6;
  int bid = blockIdx.x;
  int b = bid >> 9;
  int nbase = (bid & 511) << 7;
  size_t bN = (size_t)b * NPTS;
  const float* xb = xyz + (size_t)b*3*NPTS;
  const u16* rhTb = rhT + (bN << 6);
  int pt = tid >> 3, chk8 = (tid & 7)*8;
  const u16* cbase = rhTb + chk8;
  int l15 = lane & 15, quad = lane >> 4;
  int orow = wv*16 + l15;

  uint4 g[4];

  COOPLOAD(nbase, 0);
  __syncthreads();
  {
    int4 jj = ((const int4*)jlds[0])[pt];
    g[0] = *(const uint4*)(cbase + (((size_t)jj.x)<<6));
    g[1] = *(const uint4*)(cbase + (((size_t)jj.y)<<6));
    g[2] = *(const uint4*)(cbase + (((size_t)jj.z)<<6));
    g[3] = *(const uint4*)(cbase + (((size_t)jj.w)<<6));
  }

  for (int t = 0; t < 4; ++t){
    int n0c = nbase + (t<<5);
    bool more = (t < 3);
    int cur = t & 1, nxt = (t+1) & 1;

    if (more){ COOPLOAD(n0c + 32, nxt); }

    {
      float4 r0 = relk[cur][pt*4+0], r1 = relk[cur][pt*4+1];
      float4 r2 = relk[cur][pt*4+2], r3 = relk[cur][pt*4+3];
      float m0[8]={0,0,0,0,0,0,0,0}, mx[8]={0,0,0,0,0,0,0,0};
      float my[8]={0,0,0,0,0,0,0,0}, mz[8]={0,0,0,0,0,0,0,0};
      ACCUM(g[0], r0); ACCUM(g[1], r1); ACCUM(g[2], r2); ACCUM(g[3], r3);
      PACKROW(bext + pt*LDB2, chk8, 64);
    }
    __syncthreads();   // A: bext(t) ready; jlds/relk[nxt] ready

    if (more){
      int4 jj = ((const int4*)jlds[nxt])[pt];
      g[0] = *(const uint4*)(cbase + (((size_t)jj.x)<<6));
      g[1] = *(const uint4*)(cbase + (((size_t)jj.y)<<6));
      g[2] = *(const uint4*)(cbase + (((size_t)jj.z)<<6));
      g[3] = *(const uint4*)(cbase + (((size_t)jj.w)<<6));
    }

    f32x4 acc[2];
    #pragma unroll
    for (int nt = 0; nt < 2; ++nt) acc[nt] = (f32x4){0,0,0,0};
    #pragma unroll
    for (int s = 0; s < 8; ++s){
      bf16x8 aq = *(const bf16x8*)(Aqrh + ((s*4 + quad)*64 + orow)*8);
      #pragma unroll
      for (int nt = 0; nt < 2; ++nt){
        bf16x8 bb = *(const bf16x8*)(bext + (nt*16 + l15)*LDB2 + s*32 + quad*8);
        acc[nt] = __builtin_amdgcn_mfma_f32_16x16x32_bf16(aq, bb, acc[nt], 0, 0, 0);
      }
    }

    #pragma unroll
    for (int nt = 0; nt < 2; ++nt){
      #pragma unroll
      for (int reg = 0; reg < 4; ++reg){
        int o = wv*16 + quad*4 + reg;
        int p = nt*16 + l15;
        size_t idx = (((size_t)(b*HIDC + o))<<16) + n0c + p;
        u32 v = zq_ws[idx];
        float zf  = bf2f((u16)(v & 0xffffu));
        float qxv = bf2f((u16)(v >> 16));
        float qf = tanhf_(acc[nt][reg] + bq_out[o] + qxv);
        float hv = h[idx];
        out[idx] = (1.f - zf)*hv + zf*qf;
      }
    }
    __syncthreads();   // C: bext free for moments(t+1)
  }
}

extern "C" void kernel_launch(void* const* d_in, const int* in_sizes, int n_in,
                              void* d_out, int out_size, void* d_ws, size_t ws_size,
                              hipStream_t stream){
  const float* xyz    = (const float*)d_in[0];
  const float* h      = (const float*)d_in[1];
  const float* x      = (const float*)d_in[2];
  const int*   knn    = (const int*)d_in[3];
  const float* wz_pos = (const float*)d_in[4];
  const float* bz_pos = (const float*)d_in[5];
  const float* wz_out = (const float*)d_in[6];
  const float* bz_out = (const float*)d_in[7];
  const float* wr_pos = (const float*)d_in[8];
  const float* br_pos = (const float*)d_in[9];
  const float* wr_out = (const float*)d_in[10];
  const float* br_out = (const float*)d_in[11];
  const float* wq_pos = (const float*)d_in[12];
  const float* bq_pos = (const float*)d_in[13];
  const float* wq_out = (const float*)d_in[14];
  const float* bq_out = (const float*)d_in[15];
  float* out = (float*)d_out;

  // ws (u16 units): hxT[16777216] | rhT[8388608] | zq(u32)[8388608] | A[114688]
  u16* ws   = (u16*)d_ws;
  u16* hxT  = ws;
  u16* rhT  = ws + 16777216;
  u32* zq   = (u32*)(ws + 25165824);
  u16* A    = ws + 41943040;

  kprep<<<448, 256, 0, stream>>>(wz_out, wz_pos, bz_pos, wr_out, wr_pos, br_pos,
                                 wq_out, wq_pos, bq_pos, A);
  k_pack<<<2048, 256, 0, stream>>>(h, x, hxT);
  k_zr<<<1024, 256, 0, stream>>>(xyz, h, knn, bz_out, br_out, A, hxT, rhT, zq);
  k_q<<<1024, 256, 0, stream>>>(xyz, h, knn, bq_out, A + 98304, rhT, zq, out);
}